// Round 1
// baseline (1036.759 us; speedup 1.0000x reference)
//
#include <hip/hip_runtime.h>
#include <cstdint>

// Problem constants (setup_inputs is fixed): N=M=2048 windows, L=64 tokens,
// C=256, A=48 asy tokens, H=8 heads, dh=32, B=8 CB groups.
#define LN_EPS    1e-5f
#define SCALE_ATT 0.17677669529663688f   // 32^-0.5

#define BIGS 776   // LDS stride for 48x768 qkv buffer (bf16)
#define ZBS  264   // LDS stride for 48x256 bf16 buffer
#define HSTR 520   // LDS stride for 48x512 mlp-hidden half (bf16)

typedef __bf16 bf16x8 __attribute__((ext_vector_type(8)));
typedef float f32x4 __attribute__((ext_vector_type(4)));
typedef unsigned short us8v __attribute__((ext_vector_type(8)));

__device__ __forceinline__ unsigned short f2bf(float f) {
  unsigned int u = __builtin_bit_cast(unsigned int, f);
  u += 0x7FFFu + ((u >> 16) & 1u);           // RNE
  return (unsigned short)(u >> 16);
}
__device__ __forceinline__ float b2f(unsigned short h) {
  unsigned int u = ((unsigned int)h) << 16;
  return __builtin_bit_cast(float, u);
}
__device__ __forceinline__ bf16x8 ld_frag(const unsigned short* p) {
  us8v u = *(const us8v*)p;
  return __builtin_bit_cast(bf16x8, u);
}
__device__ __forceinline__ float wave_sum(float v) {
#pragma unroll
  for (int m = 1; m < 64; m <<= 1) v += __shfl_xor(v, m, 64);
  return v;
}

// Pack f32 weight W[K][N] -> bf16 wp[(kb*N + c)*32 + ko] = W[kb*32+ko][c]
// so an MFMA B-fragment (col=lane&15, k=(lane>>4)*8+i) is one 16B lane load.
__global__ void pack_w_kernel(const float* __restrict__ W, unsigned short* __restrict__ out,
                              int K, int Ncols) {
  int idx = blockIdx.x * 256 + threadIdx.x;
  if (idx >= K * Ncols) return;
  int kb = idx / (Ncols * 32);
  int rem = idx - kb * (Ncols * 32);
  int c = rem >> 5;
  int ko = rem & 31;
  out[idx] = f2bf(W[(kb * 32 + ko) * Ncols + c]);
}

// LN1 for padding rows (j in [48,64)) straight into d_out.
__global__ void ln1_pad_kernel(const float* __restrict__ x, float* __restrict__ out,
                               const float* __restrict__ g, const float* __restrict__ b) {
  int rid = blockIdx.x * 4 + (threadIdx.x >> 6);
  int lane = threadIdx.x & 63;
  int n = rid >> 4;
  int j = 48 + (rid & 15);
  size_t base = ((size_t)n * 64 + j) * 256 + lane * 4;
  float4 xv = *(const float4*)&x[base];
  float mu = wave_sum(xv.x + xv.y + xv.z + xv.w) * (1.f / 256.f);
  float d0 = xv.x - mu, d1 = xv.y - mu, d2 = xv.z - mu, d3 = xv.w - mu;
  float var = wave_sum(d0 * d0 + d1 * d1 + d2 * d2 + d3 * d3) * (1.f / 256.f);
  float r = rsqrtf(var + LN_EPS);
  float4 gv = *(const float4*)&g[lane * 4];
  float4 bv = *(const float4*)&b[lane * 4];
  float4 o;
  o.x = d0 * r * gv.x + bv.x;
  o.y = d1 * r * gv.y + bv.y;
  o.z = d2 * r * gv.z + bv.z;
  o.w = d3 * r * gv.w + bv.w;
  *(float4*)&out[base] = o;
}

// C(48 x ...) = A_lds(48 x 32*KB, stride lda) @ Wpack ; each wave owns CT col-tiles at col0.
template <int CT, int KB>
__device__ __forceinline__ void gemm48(const unsigned short* A, int lda,
                                       const unsigned short* __restrict__ wp, int ncols,
                                       int col0, int lane, f32x4 (&acc)[3][CT]) {
  const int r16 = lane & 15;
  const int kg = lane >> 4;
#pragma unroll
  for (int kb = 0; kb < KB; ++kb) {
    const int ka = kb * 32 + kg * 8;
    bf16x8 a0 = ld_frag(&A[r16 * lda + ka]);
    bf16x8 a1 = ld_frag(&A[(16 + r16) * lda + ka]);
    bf16x8 a2 = ld_frag(&A[(32 + r16) * lda + ka]);
#pragma unroll
    for (int ct = 0; ct < CT; ++ct) {
      const bf16x8 bfr = ld_frag(&wp[(size_t)(kb * ncols + col0 + ct * 16 + r16) * 32 + kg * 8]);
      acc[0][ct] = __builtin_amdgcn_mfma_f32_16x16x32_bf16(a0, bfr, acc[0][ct], 0, 0, 0);
      acc[1][ct] = __builtin_amdgcn_mfma_f32_16x16x32_bf16(a1, bfr, acc[1][ct], 0, 0, 0);
      acc[2][ct] = __builtin_amdgcn_mfma_f32_16x16x32_bf16(a2, bfr, acc[2][ct], 0, 0, 0);
    }
  }
}

__global__ __launch_bounds__(512) void fused_window_kernel(
    const float* __restrict__ x, float* __restrict__ out, const int* __restrict__ iw,
    const float* __restrict__ n1g, const float* __restrict__ n1b,
    const float* __restrict__ n2g, const float* __restrict__ n2b,
    const unsigned short* __restrict__ qkvp, const float* __restrict__ qkvb,
    const unsigned short* __restrict__ projp, const float* __restrict__ projb,
    const float* __restrict__ ls1, const float* __restrict__ ls2,
    const unsigned short* __restrict__ m1p, const float* __restrict__ m1b,
    const unsigned short* __restrict__ m2p, const float* __restrict__ m2b,
    float* __restrict__ gsum, const int* __restrict__ ecb) {
  __shared__ __align__(16) float zf[48 * 256];              // z (f32), later xa, later final
  __shared__ __align__(16) unsigned short zb[48 * ZBS];     // z bf16 -> o bf16 -> xa bf16
  __shared__ __align__(16) unsigned short big[48 * BIGS];   // qkv bf16 -> mlp hidden half

  const int m = blockIdx.x;
  const int n = iw[m];
  const int tid = threadIdx.x;
  const int w = tid >> 6;
  const int lane = tid & 63;
  const int r16 = lane & 15;
  const int kg = lane >> 4;
  const f32x4 vzero = {0.f, 0.f, 0.f, 0.f};

  const float* xwin = x + (size_t)n * (64 * 256);
  float* owin = out + (size_t)n * (64 * 256);

  // ---- Phase A: z = LN2(LN1(x)) for the 48 asy rows ----
  {
    float4 g1v = *(const float4*)&n1g[lane * 4];
    float4 b1v = *(const float4*)&n1b[lane * 4];
    float4 g2v = *(const float4*)&n2g[lane * 4];
    float4 b2v = *(const float4*)&n2b[lane * 4];
#pragma unroll
    for (int i = 0; i < 6; ++i) {
      int j = w * 6 + i;
      float4 xv = *(const float4*)&xwin[(size_t)j * 256 + lane * 4];
      float mu1 = wave_sum(xv.x + xv.y + xv.z + xv.w) * (1.f / 256.f);
      float d0 = xv.x - mu1, d1 = xv.y - mu1, d2 = xv.z - mu1, d3 = xv.w - mu1;
      float r1 = rsqrtf(wave_sum(d0 * d0 + d1 * d1 + d2 * d2 + d3 * d3) * (1.f / 256.f) + LN_EPS);
      float y0 = d0 * r1 * g1v.x + b1v.x, y1 = d1 * r1 * g1v.y + b1v.y;
      float y2 = d2 * r1 * g1v.z + b1v.z, y3 = d3 * r1 * g1v.w + b1v.w;
      float mu2 = wave_sum(y0 + y1 + y2 + y3) * (1.f / 256.f);
      float e0 = y0 - mu2, e1 = y1 - mu2, e2 = y2 - mu2, e3 = y3 - mu2;
      float r2 = rsqrtf(wave_sum(e0 * e0 + e1 * e1 + e2 * e2 + e3 * e3) * (1.f / 256.f) + LN_EPS);
      float z0 = e0 * r2 * g2v.x + b2v.x, z1 = e1 * r2 * g2v.y + b2v.y;
      float z2 = e2 * r2 * g2v.z + b2v.z, z3 = e3 * r2 * g2v.w + b2v.w;
      float4 zv; zv.x = z0; zv.y = z1; zv.z = z2; zv.w = z3;
      *(float4*)&zf[j * 256 + lane * 4] = zv;
      *(ushort4*)&zb[j * ZBS + lane * 4] = make_ushort4(f2bf(z0), f2bf(z1), f2bf(z2), f2bf(z3));
    }
  }
  __syncthreads();

  // ---- Phase B: QKV = z @ qkv_w + qkv_b (48x768), each wave owns 96 cols ----
  {
    f32x4 acc[3][6];
#pragma unroll
    for (int i = 0; i < 3; ++i)
#pragma unroll
      for (int j = 0; j < 6; ++j) acc[i][j] = vzero;
    gemm48<6, 8>(zb, ZBS, qkvp, 768, w * 96, lane, acc);
#pragma unroll
    for (int ct = 0; ct < 6; ++ct) {
      int col = w * 96 + ct * 16 + r16;
      float bias = qkvb[col];
#pragma unroll
      for (int rt = 0; rt < 3; ++rt)
#pragma unroll
        for (int rr = 0; rr < 4; ++rr) {
          int row = rt * 16 + kg * 4 + rr;
          big[row * BIGS + col] = f2bf(acc[rt][ct][rr] + bias);
        }
    }
  }
  __syncthreads();

  // ---- Phase C: attention (VALU). thread = (head h, query q); 48 keys, dh=32 ----
  if (tid < 384) {
    int h = tid / 48;
    int q = tid - h * 48;
    float qv[32];
#pragma unroll
    for (int dd = 0; dd < 4; ++dd) {
      us8v u = *(const us8v*)&big[q * BIGS + h * 96 + dd * 8];
#pragma unroll
      for (int i = 0; i < 8; ++i) qv[dd * 8 + i] = b2f(u[i]);
    }
    float s[48];
    float mx = -1e30f;
#pragma unroll
    for (int k = 0; k < 48; ++k) {
      float a = 0.f;
#pragma unroll
      for (int dd = 0; dd < 4; ++dd) {
        us8v u = *(const us8v*)&big[k * BIGS + h * 96 + 32 + dd * 8];
#pragma unroll
        for (int i = 0; i < 8; ++i) a += qv[dd * 8 + i] * b2f(u[i]);
      }
      a *= SCALE_ATT;
      s[k] = a;
      mx = fmaxf(mx, a);
    }
    float sum = 0.f;
#pragma unroll
    for (int k = 0; k < 48; ++k) {
      float e = __expf(s[k] - mx);
      s[k] = e;
      sum += e;
    }
    float inv = 1.f / sum;
    float o[32];
#pragma unroll
    for (int d = 0; d < 32; ++d) o[d] = 0.f;
#pragma unroll
    for (int k = 0; k < 48; ++k) {
      float p = s[k];
#pragma unroll
      for (int dd = 0; dd < 4; ++dd) {
        us8v u = *(const us8v*)&big[k * BIGS + h * 96 + 64 + dd * 8];
#pragma unroll
        for (int i = 0; i < 8; ++i) o[dd * 8 + i] += p * b2f(u[i]);
      }
    }
#pragma unroll
    for (int d = 0; d < 32; ++d) zb[q * ZBS + h * 32 + d] = f2bf(o[d] * inv);
  }
  __syncthreads();

  // ---- Phase D: proj; xa = z + ls1*(o @ proj_w + proj_b). wave owns 32 cols ----
  {
    f32x4 acc[3][2];
#pragma unroll
    for (int i = 0; i < 3; ++i)
#pragma unroll
      for (int j = 0; j < 2; ++j) acc[i][j] = vzero;
    gemm48<2, 8>(zb, ZBS, projp, 256, w * 32, lane, acc);
    __syncthreads();  // all proj reads of zb done before overwriting with xa
#pragma unroll
    for (int ct = 0; ct < 2; ++ct) {
      int col = w * 32 + ct * 16 + r16;
      float bias = projb[col];
      float l1 = ls1[col];
#pragma unroll
      for (int rt = 0; rt < 3; ++rt)
#pragma unroll
        for (int rr = 0; rr < 4; ++rr) {
          int row = rt * 16 + kg * 4 + rr;
          float xa = zf[row * 256 + col] + l1 * (acc[rt][ct][rr] + bias);
          zf[row * 256 + col] = xa;
          zb[row * ZBS + col] = f2bf(xa);
        }
    }
  }
  __syncthreads();

  // ---- Phase E: MLP, hidden (1024) in two halves of 512 ----
  f32x4 acc2[3][2];
#pragma unroll
  for (int i = 0; i < 3; ++i)
#pragma unroll
    for (int j = 0; j < 2; ++j) acc2[i][j] = vzero;
#pragma unroll 1
  for (int half = 0; half < 2; ++half) {
    f32x4 acch[3][4];
#pragma unroll
    for (int i = 0; i < 3; ++i)
#pragma unroll
      for (int j = 0; j < 4; ++j) acch[i][j] = vzero;
    gemm48<4, 8>(zb, ZBS, m1p, 1024, half * 512 + w * 64, lane, acch);
#pragma unroll
    for (int ct = 0; ct < 4; ++ct) {
      int lcol = w * 64 + ct * 16 + r16;
      float bias = m1b[half * 512 + lcol];
#pragma unroll
      for (int rt = 0; rt < 3; ++rt)
#pragma unroll
        for (int rr = 0; rr < 4; ++rr) {
          int row = rt * 16 + kg * 4 + rr;
          float hv = acch[rt][ct][rr] + bias;
          hv = 0.5f * hv * (1.0f + erff(hv * 0.70710678118654752f));  // exact gelu
          big[row * HSTR + lcol] = f2bf(hv);
        }
    }
    __syncthreads();
    gemm48<2, 16>(big, HSTR, m2p + (size_t)half * (16 * 256 * 32), 256, w * 32, lane, acc2);
    __syncthreads();
  }

  // ---- Phase F: mvec epilogue: out += fac*ls2*mvec ; CB group sums (atomics) ----
  {
    const int cb = *ecb;
    const float mfac = cb ? 0.5f : 1.0f;
    const int g = n >> 8;
#pragma unroll
    for (int ct = 0; ct < 2; ++ct) {
      int col = w * 32 + ct * 16 + r16;
      float bias = m2b[col];
      float l2 = ls2[col];
      float csum = 0.f;
#pragma unroll
      for (int rt = 0; rt < 3; ++rt)
#pragma unroll
        for (int rr = 0; rr < 4; ++rr) {
          int row = rt * 16 + kg * 4 + rr;
          float mv = acc2[rt][ct][rr] + bias;
          zf[row * 256 + col] += mfac * l2 * mv;
          csum += mv;
        }
      csum += __shfl_xor(csum, 16, 64);
      csum += __shfl_xor(csum, 32, 64);
      if (cb && kg == 0) atomicAdd(&gsum[g * 256 + col], csum);
    }
  }
  __syncthreads();

  // ---- Phase G: coalesced store of the 48 asy rows ----
#pragma unroll
  for (int i = 0; i < 6; ++i) {
    int j = w * 6 + i;
    *(float4*)&owin[(size_t)j * 256 + lane * 4] = *(const float4*)&zf[j * 256 + lane * 4];
  }
}

// out[n, j<48, :] += 0.5 * ls2 * group_mean  (group = n>>8, mean over 16384 rows)
__global__ void cb_add_kernel(float* __restrict__ out, const float* __restrict__ gsum,
                              const float* __restrict__ ls2, const int* __restrict__ ecb) {
  if (*ecb == 0) return;
  const float sc = 0.5f / 16384.0f;
  int idx = blockIdx.x * blockDim.x + threadIdx.x;
  const int total = 2048 * 48 * 64;  // float4 granules
  for (; idx < total; idx += gridDim.x * blockDim.x) {
    int n = idx / (48 * 64);
    int rem = idx - n * (48 * 64);
    int j = rem >> 6;
    int c4 = rem & 63;
    int g = n >> 8;
    float4 gs = *(const float4*)&gsum[g * 256 + c4 * 4];
    float4 l2 = *(const float4*)&ls2[c4 * 4];
    float* p = &out[((size_t)n * 64 + j) * 256 + c4 * 4];
    float4 v = *(float4*)p;
    v.x += sc * l2.x * gs.x;
    v.y += sc * l2.y * gs.y;
    v.z += sc * l2.z * gs.z;
    v.w += sc * l2.w * gs.w;
    *(float4*)p = v;
  }
}

extern "C" void kernel_launch(void* const* d_in, const int* in_sizes, int n_in,
                              void* d_out, int out_size, void* d_ws, size_t ws_size,
                              hipStream_t stream) {
  const float* x = (const float*)d_in[0];
  const int* iw = (const int*)d_in[1];
  const int* ecb = (const int*)d_in[7];
  const float* n1g = (const float*)d_in[8];
  const float* n1b = (const float*)d_in[9];
  const float* n2g = (const float*)d_in[10];
  const float* n2b = (const float*)d_in[11];
  const float* qkvw = (const float*)d_in[12];
  const float* qkvb = (const float*)d_in[13];
  const float* projw = (const float*)d_in[14];
  const float* projb = (const float*)d_in[15];
  const float* ls1 = (const float*)d_in[16];
  const float* ls2 = (const float*)d_in[17];
  const float* m1w = (const float*)d_in[18];
  const float* m1b = (const float*)d_in[19];
  const float* m2w = (const float*)d_in[20];
  const float* m2b = (const float*)d_in[21];
  float* out = (float*)d_out;

  char* ws = (char*)d_ws;
  unsigned short* qkvp = (unsigned short*)(ws);             // 256x768  -> 393216 B
  unsigned short* projp = (unsigned short*)(ws + 393216);   // 256x256  -> 131072 B
  unsigned short* m1p = (unsigned short*)(ws + 524288);     // 256x1024 -> 524288 B
  unsigned short* m2p = (unsigned short*)(ws + 1048576);    // 1024x256 -> 524288 B
  float* gsum = (float*)(ws + 1572864);                     // 8 x 256 f32

  hipMemsetAsync(gsum, 0, 8 * 256 * sizeof(float), stream);

  pack_w_kernel<<<768, 256, 0, stream>>>(qkvw, qkvp, 256, 768);
  pack_w_kernel<<<256, 256, 0, stream>>>(projw, projp, 256, 256);
  pack_w_kernel<<<1024, 256, 0, stream>>>(m1w, m1p, 256, 1024);
  pack_w_kernel<<<1024, 256, 0, stream>>>(m2w, m2p, 1024, 256);

  ln1_pad_kernel<<<8192, 256, 0, stream>>>(x, out, n1g, n1b);

  fused_window_kernel<<<2048, 512, 0, stream>>>(x, out, iw, n1g, n1b, n2g, n2b,
                                                qkvp, qkvb, projp, projb, ls1, ls2,
                                                m1p, m1b, m2p, m2b, gsum, ecb);

  cb_add_kernel<<<4096, 256, 0, stream>>>(out, gsum, ls2, ecb);
}